// Round 1
// baseline (1527.988 us; speedup 1.0000x reference)
//
#include <hip/hip_runtime.h>
#include <math.h>

#define NNODE 2048
#define NEDGE 65536
#define HIDN  256
#define NHEAD 8
#define HDIM  32
#define FFD   1024
#define NLAYER 4
#define OUTD  1280
#define NNZ_MAX (2*NEDGE + NNODE)   // 133120 upper bound on dedup'd adjacency

// ---------------------------------------------------------------- GEMM -----
// C[M,N] = A[M,K] @ B[K,N] + bias, with epilogue.
// EPI: 0 = bias, 1 = bias+gelu(exact), 2 = bias+tanh, 3 = bias + extra[row,col]
// Requires M%64==0, K%16==0, A 16B-aligned rows (K%4==0). N guarded.
#define BM 64
#define BN 64
#define BK 16

template<int EPI>
__global__ __launch_bounds__(256)
void gemm_kernel(const float* __restrict__ A, const float* __restrict__ B,
                 const float* __restrict__ bias, const float* __restrict__ extra,
                 float* __restrict__ C, int M, int N, int K)
{
    __shared__ float As[BK][BM + 4];
    __shared__ float Bs[BK][BN + 4];
    int tid = threadIdx.x;
    int bm0 = blockIdx.y * BM;
    int bn0 = blockIdx.x * BN;
    int arow = tid >> 2;         // 0..63
    int ak   = (tid & 3) << 2;   // 0,4,8,12
    int bk   = tid >> 4;         // 0..15
    int bn   = (tid & 15) << 2;  // 0..60
    int ty = tid >> 4;           // m-quad
    int tx = tid & 15;           // n-quad
    float acc[4][4] = {};
    for (int k0 = 0; k0 < K; k0 += BK) {
        const float* ap = A + (size_t)(bm0 + arow) * K + k0 + ak;
        float4 av = *(const float4*)ap;
        As[ak+0][arow] = av.x; As[ak+1][arow] = av.y;
        As[ak+2][arow] = av.z; As[ak+3][arow] = av.w;
        #pragma unroll
        for (int j = 0; j < 4; j++) {
            int col = bn0 + bn + j;
            Bs[bk][bn+j] = (col < N) ? B[(size_t)(k0 + bk) * N + col] : 0.f;
        }
        __syncthreads();
        #pragma unroll
        for (int k = 0; k < BK; k++) {
            float a[4], b[4];
            #pragma unroll
            for (int i = 0; i < 4; i++) a[i] = As[k][ty*4+i];
            #pragma unroll
            for (int j = 0; j < 4; j++) b[j] = Bs[k][tx*4+j];
            #pragma unroll
            for (int i = 0; i < 4; i++)
                #pragma unroll
                for (int j = 0; j < 4; j++)
                    acc[i][j] += a[i] * b[j];
        }
        __syncthreads();
    }
    #pragma unroll
    for (int i = 0; i < 4; i++) {
        int row = bm0 + ty*4 + i;
        #pragma unroll
        for (int j = 0; j < 4; j++) {
            int col = bn0 + tx*4 + j;
            if (col < N) {
                float v = acc[i][j] + bias[col];
                if (EPI == 1) v = 0.5f * v * (1.f + erff(v * 0.70710678118654752f));
                else if (EPI == 2) v = tanhf(v);
                else if (EPI == 3) v += extra[(size_t)row*N + col];
                C[(size_t)row*N + col] = v;
            }
        }
    }
}

// ------------------------------------------------------- adjacency / CSR ---
__global__ void adj_build(const int* __restrict__ src, const int* __restrict__ dst,
                          unsigned* __restrict__ adjbits)
{
    int t = blockIdx.x * blockDim.x + threadIdx.x;
    if (t < NEDGE) {
        int s = src[t], d = dst[t];
        atomicOr(&adjbits[(size_t)s*64 + (d >> 5)], 1u << (d & 31));
        atomicOr(&adjbits[(size_t)d*64 + (s >> 5)], 1u << (s & 31));
    }
    if (t < NNODE)
        atomicOr(&adjbits[(size_t)t*64 + (t >> 5)], 1u << (t & 31));
}

__global__ void row_rank(const unsigned* __restrict__ adjbits,
                         unsigned* __restrict__ rowcum, int* __restrict__ deg)
{
    int i = blockIdx.x * blockDim.x + threadIdx.x;
    if (i >= NNODE) return;
    unsigned c = 0;
    for (int w = 0; w < 64; w++) {
        rowcum[i*64 + w] = c;
        c += __popc(adjbits[i*64 + w]);
    }
    deg[i] = (int)c;
}

__global__ __launch_bounds__(256)
void scan_kernel(const int* __restrict__ deg, int* __restrict__ rowoff)
{
    __shared__ int part[256];
    int tid = threadIdx.x;
    int base = tid * 8;
    int local[8]; int s = 0;
    #pragma unroll
    for (int k = 0; k < 8; k++) { local[k] = s; s += deg[base + k]; }
    part[tid] = s;
    __syncthreads();
    for (int off = 1; off < 256; off <<= 1) {
        int v = (tid >= off) ? part[tid - off] : 0;
        __syncthreads();
        part[tid] += v;
        __syncthreads();
    }
    int pre = (tid == 0) ? 0 : part[tid - 1];
    #pragma unroll
    for (int k = 0; k < 8; k++) rowoff[base + k] = pre + local[k];
    if (tid == 255) rowoff[NNODE] = part[255];
}

__global__ void fill_cols(const unsigned* __restrict__ adjbits,
                          const int* __restrict__ rowoff, int* __restrict__ cols)
{
    int i = blockIdx.x * blockDim.x + threadIdx.x;
    if (i >= NNODE) return;
    int base = rowoff[i];
    for (int w = 0; w < 64; w++) {
        unsigned bits = adjbits[i*64 + w];
        while (bits) {
            int b = __ffs(bits) - 1;
            cols[base++] = w*32 + b;
            bits &= bits - 1;
        }
    }
}

// Wcomb[k,lh] = sum_c W_edge[k,c]*Wep[l,c,h];  bcomb[lh] = b_edge . Wep[l,:,h] + bep[l,h]
__global__ void wcomb_kernel(const float* __restrict__ W_edge, const float* __restrict__ b_edge,
                             const float* __restrict__ Wep, const float* __restrict__ bep,
                             float* __restrict__ Wcomb, float* __restrict__ bcomb)
{
    int t = blockIdx.x * blockDim.x + threadIdx.x;
    if (t < 64*32) {
        int k = t >> 5, lh = t & 31, l = lh >> 3, h = lh & 7;
        float acc = 0.f;
        for (int c = 0; c < HIDN; c++)
            acc += W_edge[k*HIDN + c] * Wep[l*HIDN*NHEAD + c*NHEAD + h];
        Wcomb[k*32 + lh] = acc;
    } else if (t < 64*32 + 32) {
        int lh = t - 64*32, l = lh >> 3, h = lh & 7;
        float acc = bep[l*NHEAD + h];
        for (int c = 0; c < HIDN; c++)
            acc += b_edge[c] * Wep[l*HIDN*NHEAD + c*NHEAD + h];
        bcomb[lh] = acc;
    }
}

// scatter per-edge bias into CSR slots (accumulating, matching .at[].add)
__global__ void scatter_bias(const int* __restrict__ src, const int* __restrict__ dst,
                             const unsigned* __restrict__ adjbits,
                             const unsigned* __restrict__ rowcum,
                             const int* __restrict__ rowoff,
                             const float* __restrict__ ebias, float* __restrict__ bias_csr)
{
    int t = blockIdx.x * blockDim.x + threadIdx.x;
    int e = t >> 5;
    if (e >= NEDGE) return;
    int lh = t & 31;
    int s = src[e], d = dst[e];
    unsigned wbits = adjbits[(size_t)s*64 + (d >> 5)];
    int rank = (int)rowcum[(size_t)s*64 + (d >> 5)] + __popc(wbits & ((1u << (d & 31)) - 1u));
    int slot = rowoff[s] + rank;
    atomicAdd(&bias_csr[(size_t)slot*32 + lh], ebias[(size_t)e*32 + lh]);
}

// ------------------------------------------------------- sparse attention --
// one wave per (node, head); 64 lanes = 2 neighbors x 32 dims; online softmax
__global__ __launch_bounds__(256)
void attn_kernel(const float* __restrict__ Q, const float* __restrict__ K,
                 const float* __restrict__ V, const int* __restrict__ rowoff,
                 const int* __restrict__ cols, const float* __restrict__ bias_csr,
                 float* __restrict__ ctx, int layer)
{
    int i = blockIdx.x;
    int wave = threadIdx.x >> 6;
    int head = blockIdx.y * 4 + wave;
    int lane = threadIdx.x & 63;
    int nb = lane >> 5;
    int d  = lane & 31;
    float q = Q[(size_t)i*HIDN + head*HDIM + d];
    int start = rowoff[i], end = rowoff[i+1];
    int lh = layer * NHEAD + head;
    float m = -INFINITY, ssum = 0.f, acc = 0.f;
    for (int s0 = start; s0 < end; s0 += 2) {
        int slot = s0 + nb;
        bool valid = slot < end;
        int j = valid ? cols[slot] : 0;
        float kv = K[(size_t)j*HIDN + head*HDIM + d];
        float sp = q * kv;
        sp += __shfl_xor(sp, 1);
        sp += __shfl_xor(sp, 2);
        sp += __shfl_xor(sp, 4);
        sp += __shfl_xor(sp, 8);
        sp += __shfl_xor(sp, 16);
        float s = sp * 0.17677669529663687f;   // 1/sqrt(32)
        if (valid) s += bias_csr[(size_t)slot*32 + lh];
        else       s  = -INFINITY;
        float so = __shfl_xor(s, 32);
        float mn = fmaxf(m, fmaxf(s, so));
        float sc = __expf(m - mn);
        float p  = valid ? __expf(s - mn) : 0.f;
        float po = __shfl_xor(p, 32);
        float vv = V[(size_t)j*HIDN + head*HDIM + d];
        acc  = acc * sc + p * vv;
        ssum = ssum * sc + p + po;
        m = mn;
    }
    acc += __shfl_xor(acc, 32);
    if (lane < 32)
        ctx[(size_t)i*HIDN + head*HDIM + d] = acc / ssum;
}

// ------------------------------------------------------------ layernorm ----
template<bool RES>
__global__ __launch_bounds__(256)
void ln_kernel(float* __restrict__ x, const float* __restrict__ r,
               const float* __restrict__ g, const float* __restrict__ b)
{
    __shared__ float lds[4];
    int row = blockIdx.x, c = threadIdx.x;
    float v = x[(size_t)row*HIDN + c];
    if (RES) v += r[(size_t)row*HIDN + c];
    float s = v;
    for (int mm = 1; mm < 64; mm <<= 1) s += __shfl_xor(s, mm);
    if ((c & 63) == 0) lds[c >> 6] = s;
    __syncthreads();
    float mean = (lds[0] + lds[1] + lds[2] + lds[3]) * (1.f / HIDN);
    __syncthreads();
    float dv = v - mean;
    float qq = dv * dv;
    for (int mm = 1; mm < 64; mm <<= 1) qq += __shfl_xor(qq, mm);
    if ((c & 63) == 0) lds[c >> 6] = qq;
    __syncthreads();
    float var = (lds[0] + lds[1] + lds[2] + lds[3]) * (1.f / HIDN);
    float rs = rsqrtf(var + 1e-5f);
    x[(size_t)row*HIDN + c] = dv * rs * g[c] + b[c];
}

// ------------------------------------------------------------- pooling -----
__global__ void pool_score(const float* __restrict__ t, const float* __restrict__ Wp2,
                           const float* __restrict__ bp2, float* __restrict__ s)
{
    int i = blockIdx.x * blockDim.x + threadIdx.x;
    if (i >= NNODE) return;
    float acc = bp2[0];
    for (int c = 0; c < HIDN; c++) acc += t[(size_t)i*HIDN + c] * Wp2[c];
    s[i] = acc;
}

__global__ __launch_bounds__(1024)
void softmax_nodes(const float* __restrict__ s, float* __restrict__ aw)
{
    __shared__ float lds[16];
    __shared__ float red;
    int tid = threadIdx.x;
    float a = s[tid], b = s[tid + 1024];
    float mx = fmaxf(a, b);
    for (int mm = 1; mm < 64; mm <<= 1) mx = fmaxf(mx, __shfl_xor(mx, mm));
    if ((tid & 63) == 0) lds[tid >> 6] = mx;
    __syncthreads();
    if (tid == 0) { float v = -INFINITY; for (int k = 0; k < 16; k++) v = fmaxf(v, lds[k]); red = v; }
    __syncthreads();
    mx = red;
    float ea = __expf(a - mx), eb = __expf(b - mx);
    float ss = ea + eb;
    for (int mm = 1; mm < 64; mm <<= 1) ss += __shfl_xor(ss, mm);
    __syncthreads();
    if ((tid & 63) == 0) lds[tid >> 6] = ss;
    __syncthreads();
    if (tid == 0) { float v = 0.f; for (int k = 0; k < 16; k++) v += lds[k]; red = v; }
    __syncthreads();
    ss = red;
    aw[tid] = ea / ss;
    aw[tid + 1024] = eb / ss;
}

__global__ __launch_bounds__(256)
void pool_kernel(const float* __restrict__ x, const float* __restrict__ aw,
                 float* __restrict__ g)
{
    __shared__ float l1[4], l2[4], l3[4];
    int c = blockIdx.x, tid = threadIdx.x;
    float sm = 0.f, mx = -INFINITY, ap = 0.f;
    for (int r = tid; r < NNODE; r += 256) {
        float v = x[(size_t)r*HIDN + c];
        sm += v;
        mx = fmaxf(mx, v);
        ap += v * aw[r];
    }
    for (int mm = 1; mm < 64; mm <<= 1) {
        sm += __shfl_xor(sm, mm);
        mx = fmaxf(mx, __shfl_xor(mx, mm));
        ap += __shfl_xor(ap, mm);
    }
    if ((tid & 63) == 0) { int w = tid >> 6; l1[w] = sm; l2[w] = mx; l3[w] = ap; }
    __syncthreads();
    if (tid == 0) {
        sm = l1[0] + l1[1] + l1[2] + l1[3];
        mx = fmaxf(fmaxf(l2[0], l2[1]), fmaxf(l2[2], l2[3]));
        ap = l3[0] + l3[1] + l3[2] + l3[3];
        g[c]          = sm * (1.f / NNODE);
        g[HIDN + c]   = mx;
        g[2*HIDN + c] = ap;
    }
}

// --------------------------------------------------------------- head ------
__global__ __launch_bounds__(512)
void head1(const float* __restrict__ g, const float* __restrict__ Wo1,
           const float* __restrict__ bo1, float* __restrict__ h1)
{
    __shared__ float gs[3*HIDN];
    int tid = threadIdx.x;
    for (int k = tid; k < 3*HIDN; k += 512) gs[k] = g[k];
    __syncthreads();
    float acc = bo1[tid];
    for (int k = 0; k < 3*HIDN; k++) acc += gs[k] * Wo1[(size_t)k*512 + tid];
    h1[tid] = fmaxf(acc, 0.f);
}

__global__ __launch_bounds__(256)
void head2(const float* __restrict__ h1, const float* __restrict__ Wo2,
           const float* __restrict__ bo2, float* __restrict__ out)
{
    __shared__ float hs[512];
    int tid = threadIdx.x;
    int j = blockIdx.x * 256 + tid;
    for (int k = tid; k < 512; k += 256) hs[k] = h1[k];
    __syncthreads();
    float acc = bo2[j];
    for (int k = 0; k < 512; k++) acc += hs[k] * Wo2[(size_t)k*OUTD + j];
    out[j] = acc;
}

// ------------------------------------------------------------- launch ------
extern "C" void kernel_launch(void* const* d_in, const int* in_sizes, int n_in,
                              void* d_out, int out_size, void* d_ws, size_t ws_size,
                              hipStream_t stream)
{
    const float* node_features = (const float*)d_in[0];
    const float* edge_features = (const float*)d_in[1];
    const int*   edge_index    = (const int*)d_in[2];
    const float* W_node = (const float*)d_in[3];
    const float* b_node = (const float*)d_in[4];
    const float* W_edge = (const float*)d_in[5];
    const float* b_edge = (const float*)d_in[6];
    const float* pos_emb = (const float*)d_in[7];
    const float* Wq = (const float*)d_in[8];
    const float* bq = (const float*)d_in[9];
    const float* Wk = (const float*)d_in[10];
    const float* bk = (const float*)d_in[11];
    const float* Wv = (const float*)d_in[12];
    const float* bv = (const float*)d_in[13];
    const float* Wo = (const float*)d_in[14];
    const float* bo = (const float*)d_in[15];
    const float* Wep = (const float*)d_in[16];
    const float* bep = (const float*)d_in[17];
    const float* Wf1 = (const float*)d_in[18];
    const float* bf1 = (const float*)d_in[19];
    const float* Wf2 = (const float*)d_in[20];
    const float* bf2 = (const float*)d_in[21];
    const float* g1  = (const float*)d_in[22];
    const float* be1 = (const float*)d_in[23];
    const float* g2  = (const float*)d_in[24];
    const float* be2 = (const float*)d_in[25];
    const float* g_ln = (const float*)d_in[26];
    const float* b_ln = (const float*)d_in[27];
    const float* Wp1 = (const float*)d_in[28];
    const float* bp1 = (const float*)d_in[29];
    const float* Wp2 = (const float*)d_in[30];
    const float* bp2 = (const float*)d_in[31];
    const float* Wo1 = (const float*)d_in[32];
    const float* bo1 = (const float*)d_in[33];
    const float* Wo2 = (const float*)d_in[34];
    const float* bo2 = (const float*)d_in[35];
    const int* src = edge_index;
    const int* dst = edge_index + NEDGE;

    // workspace carve (~37.5 MB)
    char* w = (char*)d_ws;
    auto carve = [&](size_t nbytes) {
        void* p = (void*)w;
        w += (nbytes + 255) & ~(size_t)255;
        return p;
    };
    float* x     = (float*)carve((size_t)NNODE*HIDN*4);
    float* bufQ  = (float*)carve((size_t)NNODE*HIDN*4);
    float* bufK  = (float*)carve((size_t)NNODE*HIDN*4);
    float* bufV  = (float*)carve((size_t)NNODE*HIDN*4);
    float* bufA  = (float*)carve((size_t)NNODE*HIDN*4);
    float* bufFF = (float*)carve((size_t)NNODE*FFD*4);   // also ebias_all [E,32] (same size)
    float* Wcomb = (float*)carve(64*32*4);
    float* bcomb = (float*)carve(32*4);
    unsigned* adjbits = (unsigned*)carve((size_t)NNODE*64*4);
    unsigned* rowcum  = (unsigned*)carve((size_t)NNODE*64*4);
    int* deg    = (int*)carve(NNODE*4);
    int* rowoff = (int*)carve((NNODE+1)*4);
    int* colsb  = (int*)carve((size_t)NNZ_MAX*4);
    float* bias_csr = (float*)carve((size_t)NNZ_MAX*32*4);
    float* sbuf  = (float*)carve(NNODE*4);
    float* awbuf = (float*)carve(NNODE*4);
    float* gbuf  = (float*)carve(3*HIDN*4);
    float* h1buf = (float*)carve(512*4);

    // ---- setup: adjacency, CSR, edge bias ----
    hipMemsetAsync(adjbits, 0, (size_t)NNODE*64*4, stream);
    hipMemsetAsync(bias_csr, 0, (size_t)NNZ_MAX*32*4, stream);
    adj_build<<<(NEDGE+255)/256, 256, 0, stream>>>(src, dst, adjbits);
    row_rank<<<NNODE/256, 256, 0, stream>>>(adjbits, rowcum, deg);
    scan_kernel<<<1, 256, 0, stream>>>(deg, rowoff);
    fill_cols<<<NNODE/256, 256, 0, stream>>>(adjbits, rowoff, colsb);
    wcomb_kernel<<<(64*32+32+255)/256, 256, 0, stream>>>(W_edge, b_edge, Wep, bep, Wcomb, bcomb);
    // ebias_all[E,32] = edge_features @ Wcomb + bcomb  (into bufFF)
    gemm_kernel<0><<<dim3(1, NEDGE/BM), 256, 0, stream>>>(edge_features, Wcomb, bcomb, nullptr, bufFF, NEDGE, 32, 64);
    scatter_bias<<<(NEDGE*32)/256, 256, 0, stream>>>(src, dst, adjbits, rowcum, rowoff, bufFF, bias_csr);
    // x = node_features @ W_node + b_node + pos_emb[:n]
    gemm_kernel<3><<<dim3(HIDN/BN, NNODE/BM), 256, 0, stream>>>(node_features, W_node, b_node, pos_emb, x, NNODE, HIDN, 128);

    // ---- transformer layers ----
    for (int l = 0; l < NLAYER; l++) {
        const float* Wql = Wq + (size_t)l*HIDN*HIDN;
        const float* Wkl = Wk + (size_t)l*HIDN*HIDN;
        const float* Wvl = Wv + (size_t)l*HIDN*HIDN;
        const float* Wol = Wo + (size_t)l*HIDN*HIDN;
        gemm_kernel<0><<<dim3(HIDN/BN, NNODE/BM), 256, 0, stream>>>(x, Wql, bq + l*HIDN, nullptr, bufQ, NNODE, HIDN, HIDN);
        gemm_kernel<0><<<dim3(HIDN/BN, NNODE/BM), 256, 0, stream>>>(x, Wkl, bk + l*HIDN, nullptr, bufK, NNODE, HIDN, HIDN);
        gemm_kernel<0><<<dim3(HIDN/BN, NNODE/BM), 256, 0, stream>>>(x, Wvl, bv + l*HIDN, nullptr, bufV, NNODE, HIDN, HIDN);
        attn_kernel<<<dim3(NNODE, 2), 256, 0, stream>>>(bufQ, bufK, bufV, rowoff, colsb, bias_csr, bufA, l);
        gemm_kernel<0><<<dim3(HIDN/BN, NNODE/BM), 256, 0, stream>>>(bufA, Wol, bo + l*HIDN, nullptr, bufQ, NNODE, HIDN, HIDN);
        ln_kernel<true><<<NNODE, 256, 0, stream>>>(x, bufQ, g1 + l*HIDN, be1 + l*HIDN);
        gemm_kernel<1><<<dim3(FFD/BN, NNODE/BM), 256, 0, stream>>>(x, Wf1 + (size_t)l*HIDN*FFD, bf1 + l*FFD, nullptr, bufFF, NNODE, FFD, HIDN);
        gemm_kernel<0><<<dim3(HIDN/BN, NNODE/BM), 256, 0, stream>>>(bufFF, Wf2 + (size_t)l*FFD*HIDN, bf2 + l*HIDN, nullptr, bufA, NNODE, HIDN, FFD);
        ln_kernel<true><<<NNODE, 256, 0, stream>>>(x, bufA, g2 + l*HIDN, be2 + l*HIDN);
    }

    // ---- final LN + pooling + head ----
    ln_kernel<false><<<NNODE, 256, 0, stream>>>(x, nullptr, g_ln, b_ln);
    gemm_kernel<2><<<dim3(HIDN/BN, NNODE/BM), 256, 0, stream>>>(x, Wp1, bp1, nullptr, bufQ, NNODE, HIDN, HIDN);
    pool_score<<<NNODE/256, 256, 0, stream>>>(bufQ, Wp2, bp2, sbuf);
    softmax_nodes<<<1, 1024, 0, stream>>>(sbuf, awbuf);
    pool_kernel<<<HIDN, 256, 0, stream>>>(x, awbuf, gbuf);
    head1<<<1, 512, 0, stream>>>(gbuf, Wo1, bo1, h1buf);
    head2<<<OUTD/256, 256, 0, stream>>>(h1buf, Wo2, bo2, (float*)d_out);
}

// Round 2
// 839.196 us; speedup vs baseline: 1.8208x; 1.8208x over previous
//
#include <hip/hip_runtime.h>
#include <math.h>

#define NNODE 2048
#define NEDGE 65536
#define HIDN  256
#define NHEAD 8
#define HDIM  32
#define FFD   1024
#define NLAYER 4
#define OUTD  1280
#define NNZ_MAX (2*NEDGE + NNODE)

typedef __attribute__((ext_vector_type(8))) short bf16x8;
typedef __attribute__((ext_vector_type(4))) float f32x4;

__device__ __forceinline__ unsigned short f2b(float f) {
    unsigned u = __float_as_uint(f);
    unsigned r = (u + 0x7fffu + ((u >> 16) & 1u)) >> 16;
    return (unsigned short)r;
}

// ----------------------------------------------------------- MFMA GEMM -----
// C[M,N] = A[M,K] @ B[K,N] + bias.  A: bf16 [M,K] row-major. Bt: bf16 [N,K]
// (pre-transposed). M%64==0, N%64==0, K%32==0.
// EPI: 0=bias, 1=bias+gelu, 2=bias+tanh, 3=bias+extra[row,col]
// OUT: 0=fp32 Cf, 1=bf16 Cb, 2=both
template<int EPI, int OUT>
__global__ __launch_bounds__(256)
void mgemm(const unsigned short* __restrict__ A, const unsigned short* __restrict__ Bt,
           const float* __restrict__ bias, const float* __restrict__ extra,
           float* __restrict__ Cf, unsigned short* __restrict__ Cb,
           int M, int N, int K)
{
    // row stride 40 bf16 (80B = 20 dwords): bank-balanced for b128 frag reads
    __shared__ __align__(16) unsigned short As[64 * 40];
    __shared__ __align__(16) unsigned short Bs[64 * 40];
    int tid = threadIdx.x;
    int bm0 = blockIdx.y * 64, bn0 = blockIdx.x * 64;
    int wave = tid >> 6, lane = tid & 63;
    int wm = (wave >> 1) * 32, wn = (wave & 1) * 32;
    int srow = tid >> 2, skoff = (tid & 3) * 8;
    int lrow = lane & 15, quad = lane >> 4;
    f32x4 acc[2][2] = {};
    for (int k0 = 0; k0 < K; k0 += 32) {
        *(uint4*)(&As[srow*40 + skoff]) = *(const uint4*)(A  + (size_t)(bm0+srow)*K + k0 + skoff);
        *(uint4*)(&Bs[srow*40 + skoff]) = *(const uint4*)(Bt + (size_t)(bn0+srow)*K + k0 + skoff);
        __syncthreads();
        bf16x8 af[2], bfr[2];
        #pragma unroll
        for (int i = 0; i < 2; i++) af[i]  = *(const bf16x8*)(&As[(wm + i*16 + lrow)*40 + quad*8]);
        #pragma unroll
        for (int j = 0; j < 2; j++) bfr[j] = *(const bf16x8*)(&Bs[(wn + j*16 + lrow)*40 + quad*8]);
        #pragma unroll
        for (int i = 0; i < 2; i++)
            #pragma unroll
            for (int j = 0; j < 2; j++)
                acc[i][j] = __builtin_amdgcn_mfma_f32_16x16x32_bf16(af[i], bfr[j], acc[i][j], 0, 0, 0);
        __syncthreads();
    }
    #pragma unroll
    for (int i = 0; i < 2; i++)
        #pragma unroll
        for (int j = 0; j < 2; j++) {
            int col = bn0 + wn + j*16 + lrow;
            float bv = bias[col];
            #pragma unroll
            for (int r = 0; r < 4; r++) {
                int row = bm0 + wm + i*16 + quad*4 + r;
                float v = acc[i][j][r] + bv;
                if (EPI == 1) v = 0.5f * v * (1.f + erff(v * 0.70710678118654752f));
                else if (EPI == 2) v = tanhf(v);
                else if (EPI == 3) v += extra[(size_t)row*N + col];
                if (OUT == 0 || OUT == 2) Cf[(size_t)row*N + col] = v;
                if (OUT == 1 || OUT == 2) Cb[(size_t)row*N + col] = f2b(v);
            }
        }
}

// ------------------------------------------------- weight prep (per call) --
// dst[n*K + k] = bf16(src[k*N + n]); batched over blockIdx.z
__global__ __launch_bounds__(256)
void transpose_bf16(const float* __restrict__ src, unsigned short* __restrict__ dst,
                    int K, int N, long srcStride, long dstStride)
{
    __shared__ unsigned short tile[32][33];
    const float* s = src + (size_t)blockIdx.z * srcStride;
    unsigned short* d = dst + (size_t)blockIdx.z * dstStride;
    int n0 = blockIdx.x * 32, k0 = blockIdx.y * 32;
    int tx = threadIdx.x & 31, ty = threadIdx.x >> 5;
    #pragma unroll
    for (int i = 0; i < 4; i++)
        tile[ty + i*8][tx] = f2b(s[(size_t)(k0 + ty + i*8) * N + n0 + tx]);
    __syncthreads();
    #pragma unroll
    for (int i = 0; i < 4; i++)
        d[(size_t)(n0 + ty + i*8) * K + k0 + tx] = tile[tx][ty + i*8];
}

__global__ void conv_bf16(const float* __restrict__ s, unsigned short* __restrict__ d, int n)
{
    int t = blockIdx.x * 256 + threadIdx.x;
    if (t < n) d[t] = f2b(s[t]);
}

__global__ void concat_qkv_bias(const float* __restrict__ bq, const float* __restrict__ bk,
                                const float* __restrict__ bv, float* __restrict__ bqkv)
{
    int t = blockIdx.x * 256 + threadIdx.x;
    if (t >= NLAYER * 768) return;
    int l = t / 768, j = t % 768;
    float v = (j < 256) ? bq[l*256 + j] : (j < 512 ? bk[l*256 + j - 256] : bv[l*256 + j - 512]);
    bqkv[t] = v;
}

// ------------------------------------------------------- adjacency / CSR ---
__global__ void adj_build(const int* __restrict__ src, const int* __restrict__ dst,
                          unsigned* __restrict__ adjbits)
{
    int t = blockIdx.x * blockDim.x + threadIdx.x;
    if (t < NEDGE) {
        int s = src[t], d = dst[t];
        atomicOr(&adjbits[(size_t)s*64 + (d >> 5)], 1u << (d & 31));
        atomicOr(&adjbits[(size_t)d*64 + (s >> 5)], 1u << (s & 31));
    }
    if (t < NNODE)
        atomicOr(&adjbits[(size_t)t*64 + (t >> 5)], 1u << (t & 31));
}

__global__ void row_rank(const unsigned* __restrict__ adjbits,
                         unsigned* __restrict__ rowcum, int* __restrict__ deg)
{
    int i = blockIdx.x * blockDim.x + threadIdx.x;
    if (i >= NNODE) return;
    unsigned c = 0;
    for (int w = 0; w < 64; w++) {
        rowcum[i*64 + w] = c;
        c += __popc(adjbits[i*64 + w]);
    }
    deg[i] = (int)c;
}

__global__ __launch_bounds__(256)
void scan_kernel(const int* __restrict__ deg, int* __restrict__ rowoff)
{
    __shared__ int part[256];
    int tid = threadIdx.x;
    int base = tid * 8;
    int local[8]; int s = 0;
    #pragma unroll
    for (int k = 0; k < 8; k++) { local[k] = s; s += deg[base + k]; }
    part[tid] = s;
    __syncthreads();
    for (int off = 1; off < 256; off <<= 1) {
        int v = (tid >= off) ? part[tid - off] : 0;
        __syncthreads();
        part[tid] += v;
        __syncthreads();
    }
    int pre = (tid == 0) ? 0 : part[tid - 1];
    #pragma unroll
    for (int k = 0; k < 8; k++) rowoff[base + k] = pre + local[k];
    if (tid == 255) rowoff[NNODE] = part[255];
}

__global__ void fill_cols(const unsigned* __restrict__ adjbits,
                          const int* __restrict__ rowoff, int* __restrict__ cols)
{
    int i = blockIdx.x * blockDim.x + threadIdx.x;
    if (i >= NNODE) return;
    int base = rowoff[i];
    for (int w = 0; w < 64; w++) {
        unsigned bits = adjbits[i*64 + w];
        while (bits) {
            int b = __ffs(bits) - 1;
            cols[base++] = w*32 + b;
            bits &= bits - 1;
        }
    }
}

__global__ void wcomb_kernel(const float* __restrict__ W_edge, const float* __restrict__ b_edge,
                             const float* __restrict__ Wep, const float* __restrict__ bep,
                             float* __restrict__ Wcomb, float* __restrict__ bcomb)
{
    int t = blockIdx.x * blockDim.x + threadIdx.x;
    if (t < 64*32) {
        int k = t >> 5, lh = t & 31, l = lh >> 3, h = lh & 7;
        float acc = 0.f;
        for (int c = 0; c < HIDN; c++)
            acc += W_edge[k*HIDN + c] * Wep[l*HIDN*NHEAD + c*NHEAD + h];
        Wcomb[k*32 + lh] = acc;
    } else if (t < 64*32 + 32) {
        int lh = t - 64*32, l = lh >> 3, h = lh & 7;
        float acc = bep[l*NHEAD + h];
        for (int c = 0; c < HIDN; c++)
            acc += b_edge[c] * Wep[l*HIDN*NHEAD + c*NHEAD + h];
        bcomb[lh] = acc;
    }
}

// ebias[e][lh] = edge_features[e,:] . Wcomb[:,lh] + bcomb[lh]
__global__ __launch_bounds__(256)
void ebias_kernel(const float* __restrict__ ef, const float* __restrict__ Wcomb,
                  const float* __restrict__ bcomb, float* __restrict__ out)
{
    __shared__ float Wl[64*32];
    __shared__ float bl[32];
    int tid = threadIdx.x;
    for (int k = tid; k < 64*32; k += 256) Wl[k] = Wcomb[k];
    if (tid < 32) bl[tid] = bcomb[tid];
    __syncthreads();
    int t = blockIdx.x * 256 + tid;
    int e = t >> 5, lh = t & 31;
    const float* f = ef + (size_t)e * 64;
    float acc = bl[lh];
    #pragma unroll
    for (int k = 0; k < 64; k++) acc += f[k] * Wl[k*32 + lh];
    out[(size_t)e*32 + lh] = acc;
}

__global__ void scatter_bias(const int* __restrict__ src, const int* __restrict__ dst,
                             const unsigned* __restrict__ adjbits,
                             const unsigned* __restrict__ rowcum,
                             const int* __restrict__ rowoff,
                             const float* __restrict__ ebias, float* __restrict__ bias_csr)
{
    int t = blockIdx.x * blockDim.x + threadIdx.x;
    int e = t >> 5;
    if (e >= NEDGE) return;
    int lh = t & 31;
    int s = src[e], d = dst[e];
    unsigned wbits = adjbits[(size_t)s*64 + (d >> 5)];
    int rank = (int)rowcum[(size_t)s*64 + (d >> 5)] + __popc(wbits & ((1u << (d & 31)) - 1u));
    int slot = rowoff[s] + rank;
    atomicAdd(&bias_csr[(size_t)slot*32 + lh], ebias[(size_t)e*32 + lh]);
}

// ------------------------------------------------------- sparse attention --
// QKV packed [node][768] fp32 (Q|K|V). Output ctx bf16 [node][256].
__global__ __launch_bounds__(256)
void attn_kernel(const float* __restrict__ QKV, const int* __restrict__ rowoff,
                 const int* __restrict__ cols, const float* __restrict__ bias_csr,
                 unsigned short* __restrict__ ctxb, int layer)
{
    int i = blockIdx.x;
    int wave = threadIdx.x >> 6;
    int head = blockIdx.y * 4 + wave;
    int lane = threadIdx.x & 63;
    int nb = lane >> 5;
    int d  = lane & 31;
    float q = QKV[(size_t)i*768 + head*HDIM + d];
    int start = rowoff[i], end = rowoff[i+1];
    int lh = layer * NHEAD + head;
    float m = -INFINITY, ssum = 0.f, acc = 0.f;
    for (int s0 = start; s0 < end; s0 += 2) {
        int slot = s0 + nb;
        bool valid = slot < end;
        int j = valid ? cols[slot] : 0;
        float kv = QKV[(size_t)j*768 + 256 + head*HDIM + d];
        float sp = q * kv;
        sp += __shfl_xor(sp, 1);
        sp += __shfl_xor(sp, 2);
        sp += __shfl_xor(sp, 4);
        sp += __shfl_xor(sp, 8);
        sp += __shfl_xor(sp, 16);
        float s = sp * 0.17677669529663687f;   // 1/sqrt(32)
        if (valid) s += bias_csr[(size_t)slot*32 + lh];
        else       s  = -INFINITY;
        float so = __shfl_xor(s, 32);
        float mn = fmaxf(m, fmaxf(s, so));
        float sc = __expf(m - mn);
        float p  = valid ? __expf(s - mn) : 0.f;
        float po = __shfl_xor(p, 32);
        float vv = QKV[(size_t)j*768 + 512 + head*HDIM + d];
        acc  = acc * sc + p * vv;
        ssum = ssum * sc + p + po;
        m = mn;
    }
    acc += __shfl_xor(acc, 32);
    if (lane < 32)
        ctxb[(size_t)i*HIDN + head*HDIM + d] = f2b(acc / ssum);
}

// ------------------------------------------------------------ layernorm ----
// x (fp32, in/out) gets LN(x [+ r]); also writes bf16 shadow xb for GEMM A.
template<bool RES>
__global__ __launch_bounds__(256)
void ln_kernel(float* __restrict__ x, const float* __restrict__ r,
               const float* __restrict__ g, const float* __restrict__ b,
               unsigned short* __restrict__ xb)
{
    __shared__ float lds[4];
    int row = blockIdx.x, c = threadIdx.x;
    float v = x[(size_t)row*HIDN + c];
    if (RES) v += r[(size_t)row*HIDN + c];
    float s = v;
    for (int mm = 1; mm < 64; mm <<= 1) s += __shfl_xor(s, mm);
    if ((c & 63) == 0) lds[c >> 6] = s;
    __syncthreads();
    float mean = (lds[0] + lds[1] + lds[2] + lds[3]) * (1.f / HIDN);
    __syncthreads();
    float dv = v - mean;
    float qq = dv * dv;
    for (int mm = 1; mm < 64; mm <<= 1) qq += __shfl_xor(qq, mm);
    if ((c & 63) == 0) lds[c >> 6] = qq;
    __syncthreads();
    float var = (lds[0] + lds[1] + lds[2] + lds[3]) * (1.f / HIDN);
    float rs = rsqrtf(var + 1e-5f);
    float o = dv * rs * g[c] + b[c];
    x[(size_t)row*HIDN + c] = o;
    xb[(size_t)row*HIDN + c] = f2b(o);
}

// ------------------------------------------------------------- pooling -----
__global__ void pool_score(const float* __restrict__ t, const float* __restrict__ Wp2,
                           const float* __restrict__ bp2, float* __restrict__ s)
{
    int i = blockIdx.x * blockDim.x + threadIdx.x;
    if (i >= NNODE) return;
    float acc = bp2[0];
    for (int c = 0; c < HIDN; c++) acc += t[(size_t)i*HIDN + c] * Wp2[c];
    s[i] = acc;
}

__global__ __launch_bounds__(1024)
void softmax_nodes(const float* __restrict__ s, float* __restrict__ aw)
{
    __shared__ float lds[16];
    __shared__ float red;
    int tid = threadIdx.x;
    float a = s[tid], b = s[tid + 1024];
    float mx = fmaxf(a, b);
    for (int mm = 1; mm < 64; mm <<= 1) mx = fmaxf(mx, __shfl_xor(mx, mm));
    if ((tid & 63) == 0) lds[tid >> 6] = mx;
    __syncthreads();
    if (tid == 0) { float v = -INFINITY; for (int k = 0; k < 16; k++) v = fmaxf(v, lds[k]); red = v; }
    __syncthreads();
    mx = red;
    float ea = __expf(a - mx), eb = __expf(b - mx);
    float ss = ea + eb;
    for (int mm = 1; mm < 64; mm <<= 1) ss += __shfl_xor(ss, mm);
    __syncthreads();
    if ((tid & 63) == 0) lds[tid >> 6] = ss;
    __syncthreads();
    if (tid == 0) { float v = 0.f; for (int k = 0; k < 16; k++) v += lds[k]; red = v; }
    __syncthreads();
    ss = red;
    aw[tid] = ea / ss;
    aw[tid + 1024] = eb / ss;
}

__global__ __launch_bounds__(256)
void pool_kernel(const float* __restrict__ x, const float* __restrict__ aw,
                 float* __restrict__ g)
{
    __shared__ float l1[4], l2[4], l3[4];
    int c = blockIdx.x, tid = threadIdx.x;
    float sm = 0.f, mx = -INFINITY, ap = 0.f;
    for (int r = tid; r < NNODE; r += 256) {
        float v = x[(size_t)r*HIDN + c];
        sm += v;
        mx = fmaxf(mx, v);
        ap += v * aw[r];
    }
    for (int mm = 1; mm < 64; mm <<= 1) {
        sm += __shfl_xor(sm, mm);
        mx = fmaxf(mx, __shfl_xor(mx, mm));
        ap += __shfl_xor(ap, mm);
    }
    if ((tid & 63) == 0) { int w = tid >> 6; l1[w] = sm; l2[w] = mx; l3[w] = ap; }
    __syncthreads();
    if (tid == 0) {
        sm = l1[0] + l1[1] + l1[2] + l1[3];
        mx = fmaxf(fmaxf(l2[0], l2[1]), fmaxf(l2[2], l2[3]));
        ap = l3[0] + l3[1] + l3[2] + l3[3];
        g[c]          = sm * (1.f / NNODE);
        g[HIDN + c]   = mx;
        g[2*HIDN + c] = ap;
    }
}

// --------------------------------------------------------------- head ------
__global__ __launch_bounds__(512)
void head1(const float* __restrict__ g, const float* __restrict__ Wo1,
           const float* __restrict__ bo1, float* __restrict__ h1)
{
    __shared__ float gs[3*HIDN];
    int tid = threadIdx.x;
    for (int k = tid; k < 3*HIDN; k += 512) gs[k] = g[k];
    __syncthreads();
    float acc = bo1[tid];
    for (int k = 0; k < 3*HIDN; k++) acc += gs[k] * Wo1[(size_t)k*512 + tid];
    h1[tid] = fmaxf(acc, 0.f);
}

__global__ __launch_bounds__(256)
void head2(const float* __restrict__ h1, const float* __restrict__ Wo2,
           const float* __restrict__ bo2, float* __restrict__ out)
{
    __shared__ float hs[512];
    int tid = threadIdx.x;
    int j = blockIdx.x * 256 + tid;
    for (int k = tid; k < 512; k += 256) hs[k] = h1[k];
    __syncthreads();
    float acc = bo2[j];
    for (int k = 0; k < 512; k++) acc += hs[k] * Wo2[(size_t)k*OUTD + j];
    out[j] = acc;
}

// ------------------------------------------------------------- launch ------
extern "C" void kernel_launch(void* const* d_in, const int* in_sizes, int n_in,
                              void* d_out, int out_size, void* d_ws, size_t ws_size,
                              hipStream_t stream)
{
    const float* node_features = (const float*)d_in[0];
    const float* edge_features = (const float*)d_in[1];
    const int*   edge_index    = (const int*)d_in[2];
    const float* W_node = (const float*)d_in[3];
    const float* b_node = (const float*)d_in[4];
    const float* W_edge = (const float*)d_in[5];
    const float* b_edge = (const float*)d_in[6];
    const float* pos_emb = (const float*)d_in[7];
    const float* Wq = (const float*)d_in[8];
    const float* bq = (const float*)d_in[9];
    const float* Wk = (const float*)d_in[10];
    const float* bk = (const float*)d_in[11];
    const float* Wv = (const float*)d_in[12];
    const float* bv = (const float*)d_in[13];
    const float* Wo = (const float*)d_in[14];
    const float* bo = (const float*)d_in[15];
    const float* Wep = (const float*)d_in[16];
    const float* bep = (const float*)d_in[17];
    const float* Wf1 = (const float*)d_in[18];
    const float* bf1 = (const float*)d_in[19];
    const float* Wf2 = (const float*)d_in[20];
    const float* bf2 = (const float*)d_in[21];
    const float* g1  = (const float*)d_in[22];
    const float* be1 = (const float*)d_in[23];
    const float* g2  = (const float*)d_in[24];
    const float* be2 = (const float*)d_in[25];
    const float* g_ln = (const float*)d_in[26];
    const float* b_ln = (const float*)d_in[27];
    const float* Wp1 = (const float*)d_in[28];
    const float* bp1 = (const float*)d_in[29];
    const float* Wp2 = (const float*)d_in[30];
    const float* bp2 = (const float*)d_in[31];
    const float* Wo1 = (const float*)d_in[32];
    const float* bo1 = (const float*)d_in[33];
    const float* Wo2 = (const float*)d_in[34];
    const float* bo2 = (const float*)d_in[35];
    const int* src = edge_index;
    const int* dst = edge_index + NEDGE;

    char* w = (char*)d_ws;
    auto carve = [&](size_t nbytes) {
        void* p = (void*)w;
        w += (nbytes + 255) & ~(size_t)255;
        return p;
    };
    float* x        = (float*)carve((size_t)NNODE*HIDN*4);
    unsigned short* xb = (unsigned short*)carve((size_t)NNODE*HIDN*2);
    float* bufQKV   = (float*)carve((size_t)NNODE*768*4);
    float* bufO     = (float*)carve((size_t)NNODE*HIDN*4);
    float* bufP     = (float*)carve((size_t)NNODE*HIDN*4);
    unsigned short* bufAb = (unsigned short*)carve((size_t)NNODE*HIDN*2);
    void*  scratchA = carve((size_t)NEDGE*32*4);  // ebias fp32 / FF bf16 alias
    float* bufE     = (float*)scratchA;
    unsigned short* bufFb = (unsigned short*)scratchA;
    float* Wcomb    = (float*)carve(64*32*4);
    float* bcomb    = (float*)carve(32*4);
    unsigned* adjbits = (unsigned*)carve((size_t)NNODE*64*4);
    unsigned* rowcum  = (unsigned*)carve((size_t)NNODE*64*4);
    int* deg    = (int*)carve(NNODE*4);
    int* rowoff = (int*)carve((NNODE+1)*4);
    int* colsb  = (int*)carve((size_t)NNZ_MAX*4);
    float* bias_csr = (float*)carve((size_t)NNZ_MAX*32*4);
    float* sbuf  = (float*)carve(NNODE*4);
    float* awbuf = (float*)carve(NNODE*4);
    float* gbuf  = (float*)carve(3*HIDN*4);
    float* h1buf = (float*)carve(512*4);
    unsigned short* nf_b  = (unsigned short*)carve((size_t)NNODE*128*2);
    unsigned short* WnT   = (unsigned short*)carve((size_t)HIDN*128*2);
    unsigned short* WqkvT = (unsigned short*)carve((size_t)NLAYER*768*HIDN*2);
    float*          bqkv  = (float*)carve((size_t)NLAYER*768*4);
    unsigned short* WoT   = (unsigned short*)carve((size_t)NLAYER*HIDN*HIDN*2);
    unsigned short* Wf1T  = (unsigned short*)carve((size_t)NLAYER*FFD*HIDN*2);
    unsigned short* Wf2T  = (unsigned short*)carve((size_t)NLAYER*HIDN*FFD*2);
    unsigned short* Wp1T  = (unsigned short*)carve((size_t)HIDN*HIDN*2);

    // ---- adjacency / CSR / edge bias ----
    hipMemsetAsync(adjbits, 0, (size_t)NNODE*64*4, stream);
    hipMemsetAsync(bias_csr, 0, (size_t)NNZ_MAX*32*4, stream);
    adj_build<<<(NEDGE+255)/256, 256, 0, stream>>>(src, dst, adjbits);
    row_rank<<<NNODE/256, 256, 0, stream>>>(adjbits, rowcum, deg);
    scan_kernel<<<1, 256, 0, stream>>>(deg, rowoff);
    fill_cols<<<NNODE/256, 256, 0, stream>>>(adjbits, rowoff, colsb);
    wcomb_kernel<<<(64*32+32+255)/256, 256, 0, stream>>>(W_edge, b_edge, Wep, bep, Wcomb, bcomb);
    ebias_kernel<<<(NEDGE*32)/256, 256, 0, stream>>>(edge_features, Wcomb, bcomb, bufE);
    scatter_bias<<<(NEDGE*32)/256, 256, 0, stream>>>(src, dst, adjbits, rowcum, rowoff, bufE, bias_csr);

    // ---- weight prep (fp32 -> bf16, transposed) ----
    conv_bf16<<<(NNODE*128)/256, 256, 0, stream>>>(node_features, nf_b, NNODE*128);
    transpose_bf16<<<dim3(HIDN/32, 128/32, 1), 256, 0, stream>>>(W_node, WnT, 128, HIDN, 0, 0);
    transpose_bf16<<<dim3(8, 8, NLAYER), 256, 0, stream>>>(Wq, WqkvT,            HIDN, HIDN, 65536, 196608);
    transpose_bf16<<<dim3(8, 8, NLAYER), 256, 0, stream>>>(Wk, WqkvT + 65536,    HIDN, HIDN, 65536, 196608);
    transpose_bf16<<<dim3(8, 8, NLAYER), 256, 0, stream>>>(Wv, WqkvT + 131072,   HIDN, HIDN, 65536, 196608);
    transpose_bf16<<<dim3(8, 8, NLAYER), 256, 0, stream>>>(Wo, WoT, HIDN, HIDN, 65536, 65536);
    transpose_bf16<<<dim3(FFD/32, HIDN/32, NLAYER), 256, 0, stream>>>(Wf1, Wf1T, HIDN, FFD, 262144, 262144);
    transpose_bf16<<<dim3(HIDN/32, FFD/32, NLAYER), 256, 0, stream>>>(Wf2, Wf2T, FFD, HIDN, 262144, 262144);
    transpose_bf16<<<dim3(8, 8, 1), 256, 0, stream>>>(Wp1, Wp1T, HIDN, HIDN, 0, 0);
    concat_qkv_bias<<<(NLAYER*768+255)/256, 256, 0, stream>>>(bq, bk, bv, bqkv);

    // ---- node encoding: x = nf @ W_node + b_node + pos_emb ----
    mgemm<3,2><<<dim3(HIDN/64, NNODE/64), 256, 0, stream>>>(nf_b, WnT, b_node, pos_emb, x, xb, NNODE, HIDN, 128);

    // ---- transformer layers ----
    for (int l = 0; l < NLAYER; l++) {
        mgemm<0,0><<<dim3(768/64, NNODE/64), 256, 0, stream>>>(
            xb, WqkvT + (size_t)l*768*HIDN, bqkv + l*768, nullptr, bufQKV, nullptr, NNODE, 768, HIDN);
        attn_kernel<<<dim3(NNODE, 2), 256, 0, stream>>>(bufQKV, rowoff, colsb, bias_csr, bufAb, l);
        mgemm<0,0><<<dim3(HIDN/64, NNODE/64), 256, 0, stream>>>(
            bufAb, WoT + (size_t)l*HIDN*HIDN, bo + l*HIDN, nullptr, bufO, nullptr, NNODE, HIDN, HIDN);
        ln_kernel<true><<<NNODE, 256, 0, stream>>>(x, bufO, g1 + l*HIDN, be1 + l*HIDN, xb);
        mgemm<1,1><<<dim3(FFD/64, NNODE/64), 256, 0, stream>>>(
            xb, Wf1T + (size_t)l*FFD*HIDN, bf1 + l*FFD, nullptr, nullptr, bufFb, NNODE, FFD, HIDN);
        mgemm<0,0><<<dim3(HIDN/64, NNODE/64), 256, 0, stream>>>(
            bufFb, Wf2T + (size_t)l*HIDN*FFD, bf2 + l*HIDN, nullptr, bufO, nullptr, NNODE, HIDN, FFD);
        ln_kernel<true><<<NNODE, 256, 0, stream>>>(x, bufO, g2 + l*HIDN, be2 + l*HIDN, xb);
    }

    // ---- final LN + pooling + head ----
    ln_kernel<false><<<NNODE, 256, 0, stream>>>(x, nullptr, g_ln, b_ln, xb);
    mgemm<2,0><<<dim3(HIDN/64, NNODE/64), 256, 0, stream>>>(xb, Wp1T, bp1, nullptr, bufP, nullptr, NNODE, HIDN, HIDN);
    pool_score<<<NNODE/256, 256, 0, stream>>>(bufP, Wp2, bp2, sbuf);
    softmax_nodes<<<1, 1024, 0, stream>>>(sbuf, awbuf);
    pool_kernel<<<HIDN, 256, 0, stream>>>(x, awbuf, gbuf);
    head1<<<1, 512, 0, stream>>>(gbuf, Wo1, bo1, h1buf);
    head2<<<OUTD/256, 256, 0, stream>>>(h1buf, Wo2, bo2, (float*)d_out);
}

// Round 3
// 554.883 us; speedup vs baseline: 2.7537x; 1.5124x over previous
//
#include <hip/hip_runtime.h>
#include <math.h>

#define NNODE 2048
#define NEDGE 65536
#define HIDN  256
#define NHEAD 8
#define HDIM  32
#define FFD   1024
#define NLAYER 4
#define OUTD  1280
#define NNZ_MAX (2*NEDGE + NNODE)

typedef __attribute__((ext_vector_type(8))) short bf16x8;
typedef __attribute__((ext_vector_type(4))) float f32x4;

__device__ __forceinline__ unsigned short f2b(float f) {
    unsigned u = __float_as_uint(f);
    unsigned r = (u + 0x7fffu + ((u >> 16) & 1u)) >> 16;
    return (unsigned short)r;
}
__device__ __forceinline__ float b2f(unsigned short u) {
    return __uint_as_float((unsigned)u << 16);
}

// ----------------------------------------------------------- MFMA GEMM -----
// C[M,N] = A[M,K] @ B[K,N] + bias.  A: bf16 [M,K] row-major. Bt: bf16 [N,K]
// (pre-transposed). M%64==0, N%64==0, K%32==0.
// EPI: 0=bias, 1=bias+gelu, 2=bias+tanh, 3=bias+extra[row,col]
// OUT: 0=fp32 Cf, 1=bf16 Cb, 2=both
template<int EPI, int OUT>
__global__ __launch_bounds__(256)
void mgemm(const unsigned short* __restrict__ A, const unsigned short* __restrict__ Bt,
           const float* __restrict__ bias, const float* __restrict__ extra,
           float* __restrict__ Cf, unsigned short* __restrict__ Cb,
           int M, int N, int K)
{
    __shared__ __align__(16) unsigned short As[64 * 40];
    __shared__ __align__(16) unsigned short Bs[64 * 40];
    int tid = threadIdx.x;
    int bm0 = blockIdx.y * 64, bn0 = blockIdx.x * 64;
    int wave = tid >> 6, lane = tid & 63;
    int wm = (wave >> 1) * 32, wn = (wave & 1) * 32;
    int srow = tid >> 2, skoff = (tid & 3) * 8;
    int lrow = lane & 15, quad = lane >> 4;
    f32x4 acc[2][2] = {};
    for (int k0 = 0; k0 < K; k0 += 32) {
        *(uint4*)(&As[srow*40 + skoff]) = *(const uint4*)(A  + (size_t)(bm0+srow)*K + k0 + skoff);
        *(uint4*)(&Bs[srow*40 + skoff]) = *(const uint4*)(Bt + (size_t)(bn0+srow)*K + k0 + skoff);
        __syncthreads();
        bf16x8 af[2], bfr[2];
        #pragma unroll
        for (int i = 0; i < 2; i++) af[i]  = *(const bf16x8*)(&As[(wm + i*16 + lrow)*40 + quad*8]);
        #pragma unroll
        for (int j = 0; j < 2; j++) bfr[j] = *(const bf16x8*)(&Bs[(wn + j*16 + lrow)*40 + quad*8]);
        #pragma unroll
        for (int i = 0; i < 2; i++)
            #pragma unroll
            for (int j = 0; j < 2; j++)
                acc[i][j] = __builtin_amdgcn_mfma_f32_16x16x32_bf16(af[i], bfr[j], acc[i][j], 0, 0, 0);
        __syncthreads();
    }
    #pragma unroll
    for (int i = 0; i < 2; i++)
        #pragma unroll
        for (int j = 0; j < 2; j++) {
            int col = bn0 + wn + j*16 + lrow;
            float bv = bias[col];
            #pragma unroll
            for (int r = 0; r < 4; r++) {
                int row = bm0 + wm + i*16 + quad*4 + r;
                float v = acc[i][j][r] + bv;
                if (EPI == 1) v = 0.5f * v * (1.f + erff(v * 0.70710678118654752f));
                else if (EPI == 2) v = tanhf(v);
                else if (EPI == 3) v += extra[(size_t)row*N + col];
                if (OUT == 0 || OUT == 2) Cf[(size_t)row*N + col] = v;
                if (OUT == 1 || OUT == 2) Cb[(size_t)row*N + col] = f2b(v);
            }
        }
}

// ------------------------------------------------- weight prep (per call) --
__global__ __launch_bounds__(256)
void transpose_bf16(const float* __restrict__ src, unsigned short* __restrict__ dst,
                    int K, int N, long srcStride, long dstStride)
{
    __shared__ unsigned short tile[32][33];
    const float* s = src + (size_t)blockIdx.z * srcStride;
    unsigned short* d = dst + (size_t)blockIdx.z * dstStride;
    int n0 = blockIdx.x * 32, k0 = blockIdx.y * 32;
    int tx = threadIdx.x & 31, ty = threadIdx.x >> 5;
    #pragma unroll
    for (int i = 0; i < 4; i++)
        tile[ty + i*8][tx] = f2b(s[(size_t)(k0 + ty + i*8) * N + n0 + tx]);
    __syncthreads();
    #pragma unroll
    for (int i = 0; i < 4; i++)
        d[(size_t)(n0 + ty + i*8) * K + k0 + tx] = tile[tx][ty + i*8];
}

__global__ void conv_bf16(const float* __restrict__ s, unsigned short* __restrict__ d, int n)
{
    int t = blockIdx.x * 256 + threadIdx.x;
    if (t < n) d[t] = f2b(s[t]);
}

__global__ void concat_qkv_bias(const float* __restrict__ bq, const float* __restrict__ bk,
                                const float* __restrict__ bv, float* __restrict__ bqkv)
{
    int t = blockIdx.x * 256 + threadIdx.x;
    if (t >= NLAYER * 768) return;
    int l = t / 768, j = t % 768;
    float v = (j < 256) ? bq[l*256 + j] : (j < 512 ? bk[l*256 + j - 256] : bv[l*256 + j - 512]);
    bqkv[t] = v;
}

// ------------------------------------------------------- adjacency / CSR ---
__global__ void adj_build(const int* __restrict__ src, const int* __restrict__ dst,
                          unsigned* __restrict__ adjbits)
{
    int t = blockIdx.x * blockDim.x + threadIdx.x;
    if (t < NEDGE) {
        int s = src[t], d = dst[t];
        atomicOr(&adjbits[(size_t)s*64 + (d >> 5)], 1u << (d & 31));
        atomicOr(&adjbits[(size_t)d*64 + (s >> 5)], 1u << (s & 31));
    }
    if (t < NNODE)
        atomicOr(&adjbits[(size_t)t*64 + (t >> 5)], 1u << (t & 31));
}

__global__ void row_rank(const unsigned* __restrict__ adjbits,
                         unsigned* __restrict__ rowcum, int* __restrict__ deg)
{
    int i = blockIdx.x * blockDim.x + threadIdx.x;
    if (i >= NNODE) return;
    unsigned c = 0;
    for (int w = 0; w < 64; w++) {
        rowcum[i*64 + w] = c;
        c += __popc(adjbits[i*64 + w]);
    }
    deg[i] = (int)c;
}

__global__ __launch_bounds__(256)
void scan_kernel(const int* __restrict__ deg, int* __restrict__ rowoff)
{
    __shared__ int part[256];
    int tid = threadIdx.x;
    int base = tid * 8;
    int local[8]; int s = 0;
    #pragma unroll
    for (int k = 0; k < 8; k++) { local[k] = s; s += deg[base + k]; }
    part[tid] = s;
    __syncthreads();
    for (int off = 1; off < 256; off <<= 1) {
        int v = (tid >= off) ? part[tid - off] : 0;
        __syncthreads();
        part[tid] += v;
        __syncthreads();
    }
    int pre = (tid == 0) ? 0 : part[tid - 1];
    #pragma unroll
    for (int k = 0; k < 8; k++) rowoff[base + k] = pre + local[k];
    if (tid == 255) rowoff[NNODE] = part[255];
}

__global__ void fill_cols(const unsigned* __restrict__ adjbits,
                          const int* __restrict__ rowoff, int* __restrict__ cols)
{
    int i = blockIdx.x * blockDim.x + threadIdx.x;
    if (i >= NNODE) return;
    int base = rowoff[i];
    for (int w = 0; w < 64; w++) {
        unsigned bits = adjbits[i*64 + w];
        while (bits) {
            int b = __ffs(bits) - 1;
            cols[base++] = w*32 + b;
            bits &= bits - 1;
        }
    }
}

__global__ void wcomb_kernel(const float* __restrict__ W_edge, const float* __restrict__ b_edge,
                             const float* __restrict__ Wep, const float* __restrict__ bep,
                             float* __restrict__ Wcomb, float* __restrict__ bcomb)
{
    int t = blockIdx.x * blockDim.x + threadIdx.x;
    if (t < 64*32) {
        int k = t >> 5, lh = t & 31, l = lh >> 3, h = lh & 7;
        float acc = 0.f;
        for (int c = 0; c < HIDN; c++)
            acc += W_edge[k*HIDN + c] * Wep[l*HIDN*NHEAD + c*NHEAD + h];
        Wcomb[k*32 + lh] = acc;
    } else if (t < 64*32 + 32) {
        int lh = t - 64*32, l = lh >> 3, h = lh & 7;
        float acc = bep[l*NHEAD + h];
        for (int c = 0; c < HIDN; c++)
            acc += b_edge[c] * Wep[l*HIDN*NHEAD + c*NHEAD + h];
        bcomb[lh] = acc;
    }
}

__global__ __launch_bounds__(256)
void ebias_kernel(const float* __restrict__ ef, const float* __restrict__ Wcomb,
                  const float* __restrict__ bcomb, float* __restrict__ out)
{
    __shared__ float Wl[64*32];
    __shared__ float bl[32];
    int tid = threadIdx.x;
    for (int k = tid; k < 64*32; k += 256) Wl[k] = Wcomb[k];
    if (tid < 32) bl[tid] = bcomb[tid];
    __syncthreads();
    int t = blockIdx.x * 256 + tid;
    int e = t >> 5, lh = t & 31;
    const float* f = ef + (size_t)e * 64;
    float acc = bl[lh];
    #pragma unroll
    for (int k = 0; k < 64; k++) acc += f[k] * Wl[k*32 + lh];
    out[(size_t)e*32 + lh] = acc;
}

__global__ void scatter_bias(const int* __restrict__ src, const int* __restrict__ dst,
                             const unsigned* __restrict__ adjbits,
                             const unsigned* __restrict__ rowcum,
                             const int* __restrict__ rowoff,
                             const float* __restrict__ ebias, float* __restrict__ bias_csr)
{
    int t = blockIdx.x * blockDim.x + threadIdx.x;
    int e = t >> 5;
    if (e >= NEDGE) return;
    int lh = t & 31;
    int s = src[e], d = dst[e];
    unsigned wbits = adjbits[(size_t)s*64 + (d >> 5)];
    int rank = (int)rowcum[(size_t)s*64 + (d >> 5)] + __popc(wbits & ((1u << (d & 31)) - 1u));
    int slot = rowoff[s] + rank;
    atomicAdd(&bias_csr[(size_t)slot*32 + lh], ebias[(size_t)e*32 + lh]);
}

// ------------------------------------------------------- sparse attention --
// One block per node; 4 waves split the neighbor list; each wave handles all
// 8 heads: lane = head*8 + dimgroup (4 dims/lane). QKV bf16 packed [n][768].
// Online softmax per wave, merged across waves via LDS.
__global__ __launch_bounds__(256)
void attn_kernel(const unsigned short* __restrict__ QKVb, const int* __restrict__ rowoff,
                 const int* __restrict__ cols, const float* __restrict__ bias_csr,
                 unsigned short* __restrict__ ctxb, int layer)
{
    __shared__ float mS[4][8], lS[4][8];
    __shared__ __align__(16) float accS[4][256];
    int i = blockIdx.x;
    int tid = threadIdx.x;
    int w = tid >> 6, lane = tid & 63;
    int h = lane >> 3;
    int off = lane * 4;               // == h*32 + dg*4 within a 256-wide row
    ushort4 qu = *(const ushort4*)(QKVb + (size_t)i*768 + off);
    float4 qf = { b2f(qu.x), b2f(qu.y), b2f(qu.z), b2f(qu.w) };
    int start = rowoff[i], end = rowoff[i+1];
    int lh0 = layer * 8 + h;
    float m = -INFINITY, l = 0.f;
    float4 acc = {0.f, 0.f, 0.f, 0.f};
    for (int c0 = start + w; c0 < end; c0 += 256) {
        int myslot = c0 + 4*lane;
        int mycol = (myslot < end) ? cols[myslot] : 0;
        int lim = min(end, c0 + 256);
        int it = 0;
        for (int slot = c0; slot < lim; slot += 4, ++it) {
            int j = __shfl(mycol, it);
            ushort4 ku = *(const ushort4*)(QKVb + (size_t)j*768 + 256 + off);
            float s = qf.x*b2f(ku.x) + qf.y*b2f(ku.y) + qf.z*b2f(ku.z) + qf.w*b2f(ku.w);
            s += __shfl_xor(s, 1);
            s += __shfl_xor(s, 2);
            s += __shfl_xor(s, 4);
            s = s * 0.17677669529663687f + bias_csr[(size_t)slot*32 + lh0];
            float mn = fmaxf(m, s);
            float sc = __expf(m - mn);
            float p  = __expf(s - mn);
            ushort4 vu = *(const ushort4*)(QKVb + (size_t)j*768 + 512 + off);
            acc.x = acc.x*sc + p*b2f(vu.x);
            acc.y = acc.y*sc + p*b2f(vu.y);
            acc.z = acc.z*sc + p*b2f(vu.z);
            acc.w = acc.w*sc + p*b2f(vu.w);
            l = l*sc + p;
            m = mn;
        }
    }
    if ((lane & 7) == 0) { mS[w][h] = m; lS[w][h] = l; }
    *(float4*)&accS[w][off] = acc;
    __syncthreads();
    if (w == 0) {
        float m0 = mS[0][h], m1 = mS[1][h], m2 = mS[2][h], m3 = mS[3][h];
        float mx = fmaxf(fmaxf(m0, m1), fmaxf(m2, m3));
        float e0 = (m0 == -INFINITY) ? 0.f : __expf(m0 - mx);
        float e1 = (m1 == -INFINITY) ? 0.f : __expf(m1 - mx);
        float e2 = (m2 == -INFINITY) ? 0.f : __expf(m2 - mx);
        float e3 = (m3 == -INFINITY) ? 0.f : __expf(m3 - mx);
        float ls = lS[0][h]*e0 + lS[1][h]*e1 + lS[2][h]*e2 + lS[3][h]*e3;
        float4 a0 = *(float4*)&accS[0][off];
        float4 a1 = *(float4*)&accS[1][off];
        float4 a2 = *(float4*)&accS[2][off];
        float4 a3 = *(float4*)&accS[3][off];
        float inv = 1.f / ls;
        ushort4 o;
        o.x = f2b((a0.x*e0 + a1.x*e1 + a2.x*e2 + a3.x*e3) * inv);
        o.y = f2b((a0.y*e0 + a1.y*e1 + a2.y*e2 + a3.y*e3) * inv);
        o.z = f2b((a0.z*e0 + a1.z*e1 + a2.z*e2 + a3.z*e3) * inv);
        o.w = f2b((a0.w*e0 + a1.w*e1 + a2.w*e2 + a3.w*e3) * inv);
        *(ushort4*)(ctxb + (size_t)i*HIDN + off) = o;
    }
}

// ------------------------------------------------------------ layernorm ----
template<bool RES>
__global__ __launch_bounds__(256)
void ln_kernel(float* __restrict__ x, const float* __restrict__ r,
               const float* __restrict__ g, const float* __restrict__ b,
               unsigned short* __restrict__ xb)
{
    __shared__ float lds[4];
    int row = blockIdx.x, c = threadIdx.x;
    float v = x[(size_t)row*HIDN + c];
    if (RES) v += r[(size_t)row*HIDN + c];
    float s = v;
    for (int mm = 1; mm < 64; mm <<= 1) s += __shfl_xor(s, mm);
    if ((c & 63) == 0) lds[c >> 6] = s;
    __syncthreads();
    float mean = (lds[0] + lds[1] + lds[2] + lds[3]) * (1.f / HIDN);
    __syncthreads();
    float dv = v - mean;
    float qq = dv * dv;
    for (int mm = 1; mm < 64; mm <<= 1) qq += __shfl_xor(qq, mm);
    if ((c & 63) == 0) lds[c >> 6] = qq;
    __syncthreads();
    float var = (lds[0] + lds[1] + lds[2] + lds[3]) * (1.f / HIDN);
    float rs = rsqrtf(var + 1e-5f);
    float o = dv * rs * g[c] + b[c];
    x[(size_t)row*HIDN + c] = o;
    xb[(size_t)row*HIDN + c] = f2b(o);
}

// ------------------------------------------------------------- pooling -----
__global__ void pool_score(const float* __restrict__ t, const float* __restrict__ Wp2,
                           const float* __restrict__ bp2, float* __restrict__ s)
{
    int i = blockIdx.x * blockDim.x + threadIdx.x;
    if (i >= NNODE) return;
    float acc = bp2[0];
    for (int c = 0; c < HIDN; c++) acc += t[(size_t)i*HIDN + c] * Wp2[c];
    s[i] = acc;
}

__global__ __launch_bounds__(1024)
void softmax_nodes(const float* __restrict__ s, float* __restrict__ aw)
{
    __shared__ float lds[16];
    __shared__ float red;
    int tid = threadIdx.x;
    float a = s[tid], b = s[tid + 1024];
    float mx = fmaxf(a, b);
    for (int mm = 1; mm < 64; mm <<= 1) mx = fmaxf(mx, __shfl_xor(mx, mm));
    if ((tid & 63) == 0) lds[tid >> 6] = mx;
    __syncthreads();
    if (tid == 0) { float v = -INFINITY; for (int k = 0; k < 16; k++) v = fmaxf(v, lds[k]); red = v; }
    __syncthreads();
    mx = red;
    float ea = __expf(a - mx), eb = __expf(b - mx);
    float ss = ea + eb;
    for (int mm = 1; mm < 64; mm <<= 1) ss += __shfl_xor(ss, mm);
    __syncthreads();
    if ((tid & 63) == 0) lds[tid >> 6] = ss;
    __syncthreads();
    if (tid == 0) { float v = 0.f; for (int k = 0; k < 16; k++) v += lds[k]; red = v; }
    __syncthreads();
    ss = red;
    aw[tid] = ea / ss;
    aw[tid + 1024] = eb / ss;
}

__global__ __launch_bounds__(256)
void pool_kernel(const float* __restrict__ x, const float* __restrict__ aw,
                 float* __restrict__ g)
{
    __shared__ float l1[4], l2[4], l3[4];
    int c = blockIdx.x, tid = threadIdx.x;
    float sm = 0.f, mx = -INFINITY, ap = 0.f;
    for (int r = tid; r < NNODE; r += 256) {
        float v = x[(size_t)r*HIDN + c];
        sm += v;
        mx = fmaxf(mx, v);
        ap += v * aw[r];
    }
    for (int mm = 1; mm < 64; mm <<= 1) {
        sm += __shfl_xor(sm, mm);
        mx = fmaxf(mx, __shfl_xor(mx, mm));
        ap += __shfl_xor(ap, mm);
    }
    if ((tid & 63) == 0) { int w = tid >> 6; l1[w] = sm; l2[w] = mx; l3[w] = ap; }
    __syncthreads();
    if (tid == 0) {
        sm = l1[0] + l1[1] + l1[2] + l1[3];
        mx = fmaxf(fmaxf(l2[0], l2[1]), fmaxf(l2[2], l2[3]));
        ap = l3[0] + l3[1] + l3[2] + l3[3];
        g[c]          = sm * (1.f / NNODE);
        g[HIDN + c]   = mx;
        g[2*HIDN + c] = ap;
    }
}

// --------------------------------------------------------------- head ------
__global__ __launch_bounds__(512)
void head1(const float* __restrict__ g, const float* __restrict__ Wo1,
           const float* __restrict__ bo1, float* __restrict__ h1)
{
    __shared__ float gs[3*HIDN];
    int tid = threadIdx.x;
    for (int k = tid; k < 3*HIDN; k += 512) gs[k] = g[k];
    __syncthreads();
    float acc = bo1[tid];
    for (int k = 0; k < 3*HIDN; k++) acc += gs[k] * Wo1[(size_t)k*512 + tid];
    h1[tid] = fmaxf(acc, 0.f);
}

__global__ __launch_bounds__(256)
void head2(const float* __restrict__ h1, const float* __restrict__ Wo2,
           const float* __restrict__ bo2, float* __restrict__ out)
{
    __shared__ float hs[512];
    int tid = threadIdx.x;
    int j = blockIdx.x * 256 + tid;
    for (int k = tid; k < 512; k += 256) hs[k] = h1[k];
    __syncthreads();
    float acc = bo2[j];
    for (int k = 0; k < 512; k++) acc += hs[k] * Wo2[(size_t)k*OUTD + j];
    out[j] = acc;
}

// ------------------------------------------------------------- launch ------
extern "C" void kernel_launch(void* const* d_in, const int* in_sizes, int n_in,
                              void* d_out, int out_size, void* d_ws, size_t ws_size,
                              hipStream_t stream)
{
    const float* node_features = (const float*)d_in[0];
    const float* edge_features = (const float*)d_in[1];
    const int*   edge_index    = (const int*)d_in[2];
    const float* W_node = (const float*)d_in[3];
    const float* b_node = (const float*)d_in[4];
    const float* W_edge = (const float*)d_in[5];
    const float* b_edge = (const float*)d_in[6];
    const float* pos_emb = (const float*)d_in[7];
    const float* Wq = (const float*)d_in[8];
    const float* bq = (const float*)d_in[9];
    const float* Wk = (const float*)d_in[10];
    const float* bk = (const float*)d_in[11];
    const float* Wv = (const float*)d_in[12];
    const float* bv = (const float*)d_in[13];
    const float* Wo = (const float*)d_in[14];
    const float* bo = (const float*)d_in[15];
    const float* Wep = (const float*)d_in[16];
    const float* bep = (const float*)d_in[17];
    const float* Wf1 = (const float*)d_in[18];
    const float* bf1 = (const float*)d_in[19];
    const float* Wf2 = (const float*)d_in[20];
    const float* bf2 = (const float*)d_in[21];
    const float* g1  = (const float*)d_in[22];
    const float* be1 = (const float*)d_in[23];
    const float* g2  = (const float*)d_in[24];
    const float* be2 = (const float*)d_in[25];
    const float* g_ln = (const float*)d_in[26];
    const float* b_ln = (const float*)d_in[27];
    const float* Wp1 = (const float*)d_in[28];
    const float* bp1 = (const float*)d_in[29];
    const float* Wp2 = (const float*)d_in[30];
    const float* bp2 = (const float*)d_in[31];
    const float* Wo1 = (const float*)d_in[32];
    const float* bo1 = (const float*)d_in[33];
    const float* Wo2 = (const float*)d_in[34];
    const float* bo2 = (const float*)d_in[35];
    const int* src = edge_index;
    const int* dst = edge_index + NEDGE;

    char* w = (char*)d_ws;
    auto carve = [&](size_t nbytes) {
        void* p = (void*)w;
        w += (nbytes + 255) & ~(size_t)255;
        return p;
    };
    float* x        = (float*)carve((size_t)NNODE*HIDN*4);
    unsigned short* xb = (unsigned short*)carve((size_t)NNODE*HIDN*2);
    unsigned short* bufQKVb = (unsigned short*)carve((size_t)NNODE*768*2);
    float* bufO     = (float*)carve((size_t)NNODE*HIDN*4);
    float* bufP     = (float*)carve((size_t)NNODE*HIDN*4);
    unsigned short* bufAb = (unsigned short*)carve((size_t)NNODE*HIDN*2);
    void*  scratchA = carve((size_t)NEDGE*32*4);  // ebias fp32 / FF bf16 alias
    float* bufE     = (float*)scratchA;
    unsigned short* bufFb = (unsigned short*)scratchA;
    float* Wcomb    = (float*)carve(64*32*4);
    float* bcomb    = (float*)carve(32*4);
    unsigned* adjbits = (unsigned*)carve((size_t)NNODE*64*4);
    unsigned* rowcum  = (unsigned*)carve((size_t)NNODE*64*4);
    int* deg    = (int*)carve(NNODE*4);
    int* rowoff = (int*)carve((NNODE+1)*4);
    int* colsb  = (int*)carve((size_t)NNZ_MAX*4);
    float* bias_csr = (float*)carve((size_t)NNZ_MAX*32*4);
    float* sbuf  = (float*)carve(NNODE*4);
    float* awbuf = (float*)carve(NNODE*4);
    float* gbuf  = (float*)carve(3*HIDN*4);
    float* h1buf = (float*)carve(512*4);
    unsigned short* nf_b  = (unsigned short*)carve((size_t)NNODE*128*2);
    unsigned short* WnT   = (unsigned short*)carve((size_t)HIDN*128*2);
    unsigned short* WqkvT = (unsigned short*)carve((size_t)NLAYER*768*HIDN*2);
    float*          bqkv  = (float*)carve((size_t)NLAYER*768*4);
    unsigned short* WoT   = (unsigned short*)carve((size_t)NLAYER*HIDN*HIDN*2);
    unsigned short* Wf1T  = (unsigned short*)carve((size_t)NLAYER*FFD*HIDN*2);
    unsigned short* Wf2T  = (unsigned short*)carve((size_t)NLAYER*HIDN*FFD*2);
    unsigned short* Wp1T  = (unsigned short*)carve((size_t)HIDN*HIDN*2);

    // ---- adjacency / CSR / edge bias ----
    hipMemsetAsync(adjbits, 0, (size_t)NNODE*64*4, stream);
    hipMemsetAsync(bias_csr, 0, (size_t)NNZ_MAX*32*4, stream);
    adj_build<<<(NEDGE+255)/256, 256, 0, stream>>>(src, dst, adjbits);
    row_rank<<<NNODE/256, 256, 0, stream>>>(adjbits, rowcum, deg);
    scan_kernel<<<1, 256, 0, stream>>>(deg, rowoff);
    fill_cols<<<NNODE/256, 256, 0, stream>>>(adjbits, rowoff, colsb);
    wcomb_kernel<<<(64*32+32+255)/256, 256, 0, stream>>>(W_edge, b_edge, Wep, bep, Wcomb, bcomb);
    ebias_kernel<<<(NEDGE*32)/256, 256, 0, stream>>>(edge_features, Wcomb, bcomb, bufE);
    scatter_bias<<<(NEDGE*32)/256, 256, 0, stream>>>(src, dst, adjbits, rowcum, rowoff, bufE, bias_csr);

    // ---- weight prep (fp32 -> bf16, transposed) ----
    conv_bf16<<<(NNODE*128)/256, 256, 0, stream>>>(node_features, nf_b, NNODE*128);
    transpose_bf16<<<dim3(HIDN/32, 128/32, 1), 256, 0, stream>>>(W_node, WnT, 128, HIDN, 0, 0);
    transpose_bf16<<<dim3(8, 8, NLAYER), 256, 0, stream>>>(Wq, WqkvT,            HIDN, HIDN, 65536, 196608);
    transpose_bf16<<<dim3(8, 8, NLAYER), 256, 0, stream>>>(Wk, WqkvT + 65536,    HIDN, HIDN, 65536, 196608);
    transpose_bf16<<<dim3(8, 8, NLAYER), 256, 0, stream>>>(Wv, WqkvT + 131072,   HIDN, HIDN, 65536, 196608);
    transpose_bf16<<<dim3(8, 8, NLAYER), 256, 0, stream>>>(Wo, WoT, HIDN, HIDN, 65536, 65536);
    transpose_bf16<<<dim3(FFD/32, HIDN/32, NLAYER), 256, 0, stream>>>(Wf1, Wf1T, HIDN, FFD, 262144, 262144);
    transpose_bf16<<<dim3(HIDN/32, FFD/32, NLAYER), 256, 0, stream>>>(Wf2, Wf2T, FFD, HIDN, 262144, 262144);
    transpose_bf16<<<dim3(8, 8, 1), 256, 0, stream>>>(Wp1, Wp1T, HIDN, HIDN, 0, 0);
    concat_qkv_bias<<<(NLAYER*768+255)/256, 256, 0, stream>>>(bq, bk, bv, bqkv);

    // ---- node encoding: x = nf @ W_node + b_node + pos_emb ----
    mgemm<3,2><<<dim3(HIDN/64, NNODE/64), 256, 0, stream>>>(nf_b, WnT, b_node, pos_emb, x, xb, NNODE, HIDN, 128);

    // ---- transformer layers ----
    for (int l = 0; l < NLAYER; l++) {
        mgemm<0,1><<<dim3(768/64, NNODE/64), 256, 0, stream>>>(
            xb, WqkvT + (size_t)l*768*HIDN, bqkv + l*768, nullptr, nullptr, bufQKVb, NNODE, 768, HIDN);
        attn_kernel<<<NNODE, 256, 0, stream>>>(bufQKVb, rowoff, colsb, bias_csr, bufAb, l);
        mgemm<0,0><<<dim3(HIDN/64, NNODE/64), 256, 0, stream>>>(
            bufAb, WoT + (size_t)l*HIDN*HIDN, bo + l*HIDN, nullptr, bufO, nullptr, NNODE, HIDN, HIDN);
        ln_kernel<true><<<NNODE, 256, 0, stream>>>(x, bufO, g1 + l*HIDN, be1 + l*HIDN, xb);
        mgemm<1,1><<<dim3(FFD/64, NNODE/64), 256, 0, stream>>>(
            xb, Wf1T + (size_t)l*FFD*HIDN, bf1 + l*FFD, nullptr, nullptr, bufFb, NNODE, FFD, HIDN);
        mgemm<0,0><<<dim3(HIDN/64, NNODE/64), 256, 0, stream>>>(
            bufFb, Wf2T + (size_t)l*HIDN*FFD, bf2 + l*HIDN, nullptr, bufO, nullptr, NNODE, HIDN, FFD);
        ln_kernel<true><<<NNODE, 256, 0, stream>>>(x, bufO, g2 + l*HIDN, be2 + l*HIDN, xb);
    }

    // ---- final LN + pooling + head ----
    ln_kernel<false><<<NNODE, 256, 0, stream>>>(x, nullptr, g_ln, b_ln, xb);
    mgemm<2,0><<<dim3(HIDN/64, NNODE/64), 256, 0, stream>>>(xb, Wp1T, bp1, nullptr, bufP, nullptr, NNODE, HIDN, HIDN);
    pool_score<<<NNODE/256, 256, 0, stream>>>(bufP, Wp2, bp2, sbuf);
    softmax_nodes<<<1, 1024, 0, stream>>>(sbuf, awbuf);
    pool_kernel<<<HIDN, 256, 0, stream>>>(x, awbuf, gbuf);
    head1<<<1, 512, 0, stream>>>(gbuf, Wo1, bo1, h1buf);
    head2<<<OUTD/256, 256, 0, stream>>>(h1buf, Wo2, bo2, (float*)d_out);
}